// Round 9
// baseline (155.711 us; speedup 1.0000x reference)
//
#include <hip/hip_runtime.h>
#include <cmath>

// ProtICU on MI355X — round 14: chunk 8 -> 4, 8 independent block-chains/CU.
// r13 post-mortem: 2x waves inside the same 4 lockstep chains = flat (46us @ 65%
// occupancy) -> duration tracks per-block chain length x resident CHAINS, not
// waves. Replay the proven r5->r7 lever: halve the chunk. Grid (64,32)=2048
// blocks; LDS squeezed to 20.1 KB so 8 blocks/CU resident = exactly one round.
//  * s_x 60 rows x 104 (conv1 row-clamped at 59; c1 rows >=56 are garbage and
//    discarded by the rr<28 pool guard — same pattern as conv2's clamp).
//  * s_h1 28 rows x 136. Strides stay 104/136 (16B-aligned for ds_read_b128).
//  * s_cb evicted (3 KB): biases/pn are hoisted 16B global loads in epilogues.
//  * conv structure/head/prep/finalize byte-identical to r11 otherwise.
// L2 note: A-frags re-read per block -> 2048 x 536 KB = 1.1 GB L2 traffic,
// ~32 us floor at the 34.5 TB/s L2 ceiling. That is this design's limit.

typedef __attribute__((ext_vector_type(8))) short short8;
typedef __attribute__((ext_vector_type(4))) float f32x4;

__device__ __forceinline__ unsigned short f2bf(float v) {
    union { float f; unsigned u; } x; x.f = v;
    unsigned r = x.u + 0x7fffu + ((x.u >> 16) & 1u);   // RNE
    return (unsigned short)(r >> 16);
}
__device__ __forceinline__ float bf2f(unsigned short b) {
    union { unsigned u; float f; } x; x.u = ((unsigned)b) << 16;
    return x.f;
}

// ---------------------------------------------------------------------------
// Weight packing into MFMA A-fragment order (16x16x32):
// lane holds A[m = mf*16 + (lane&15)][k = cc*32 + (lane>>4)*8 + j]
// conv: dst[((cc*5+kk)*8+mf)*64+lane][8] = W[m][c][kk]   (c >= C -> 0)
// mat : dst[((cc)*8+mf)*64+lane][8] = M[m][c]
// ---------------------------------------------------------------------------
__device__ void pack_conv_w(int t, int total, const float* __restrict__ W, int C,
                            unsigned short* __restrict__ dst)
{
    if (t >= total) return;
    int lane = t & 63, rest = t >> 6;
    int mf = rest & 7; rest >>= 3;
    int kk = rest % 5, cc = rest / 5;
    int m = mf * 16 + (lane & 15);
    int cb = cc * 32 + (lane >> 4) * 8;
    unsigned short v[8];
#pragma unroll
    for (int j = 0; j < 8; ++j) {
        int c = cb + j;
        v[j] = (c < C) ? f2bf(W[((size_t)m * C + c) * 5 + kk]) : (unsigned short)0;
    }
    *(uint4*)&dst[(size_t)t * 8] = *(uint4*)v;
}

__device__ void pack_mat(int t, const float* __restrict__ M, unsigned short* __restrict__ dst)
{
    if (t >= 2048) return;
    int lane = t & 63, mf = (t >> 6) & 7, cc = t >> 9;
    int m = mf * 16 + (lane & 15);
    int c0 = cc * 32 + (lane >> 4) * 8;
    unsigned short v[8];
#pragma unroll
    for (int j = 0; j < 8; ++j) v[j] = f2bf(M[(size_t)m * 128 + c0 + j]);
    *(uint4*)&dst[(size_t)t * 8] = *(uint4*)v;
}

__global__ __launch_bounds__(256)
void prep_weights_kernel(const float* __restrict__ W1, const float* __restrict__ W2,
                         const float* __restrict__ W3, const float* __restrict__ Wo1,
                         const float* __restrict__ Wo2, const float* __restrict__ protos,
                         unsigned short* A1, unsigned short* A2, unsigned short* A3,
                         unsigned short* AW1, unsigned short* AW2, unsigned short* AP,
                         float* pn, unsigned* pm_bits)
{
    int t = blockIdx.x * 256 + threadIdx.x;
    switch (blockIdx.y) {
    case 0: pack_conv_w(t, 7680,  W1, 76,  A1); break;
    case 1: pack_conv_w(t, 10240, W2, 128, A2); break;
    case 2: pack_conv_w(t, 10240, W3, 128, A3); break;
    case 3: pack_mat(t, Wo1, AW1); break;
    case 4: pack_mat(t, Wo2, AW2); break;
    case 5: pack_mat(t, protos, AP); break;
    case 6:
        if (t < 128) {
            float s = 0.f;
            for (int d = 0; d < 128; ++d) {
                float v = bf2f(f2bf(protos[(size_t)t * 128 + d]));
                s = fmaf(v, v, s);
            }
            pn[t] = s;
        }
        break;
    case 7:
        if (t < 4096) pm_bits[t] = 0x7F800000u;   // +inf init for atomicMin
        break;
    }
}

// ---------------------------------------------------------------------------
// Conv K-loop (r7 form): wave computes MF m-frags (mf0..mf0+MF-1) x NJ*16 rows
// at nbase. B row (local) = nbase + j*16 + lc + kk, clamped to ROWMAX if >=0.
// ---------------------------------------------------------------------------
template <int MF, int NJ, int NCC, int STRIDE, int ROWMAX>
__device__ __forceinline__ void conv_k(const unsigned short* __restrict__ Af,
                                       const unsigned short* __restrict__ sIn,
                                       int nbase, int mf0, int lane,
                                       f32x4 (&acc)[MF][NJ])
{
    const int lc = lane & 15;
    const int lk = (lane >> 4) * 8;
#pragma unroll
    for (int i = 0; i < MF; ++i)
#pragma unroll
        for (int j = 0; j < NJ; ++j) acc[i][j] = (f32x4){0.f, 0.f, 0.f, 0.f};

    for (int cc = 0; cc < NCC; ++cc) {
#pragma unroll
        for (int kk = 0; kk < 5; ++kk) {
            const int step = cc * 5 + kk;
            short8 a[MF];
#pragma unroll
            for (int i = 0; i < MF; ++i)
                a[i] = *(const short8*)&Af[(((size_t)step * 8 + mf0 + i) * 64 + lane) * 8];
            short8 bb[NJ];
#pragma unroll
            for (int j = 0; j < NJ; ++j) {
                int row = nbase + j * 16 + lc + kk;
                if (ROWMAX >= 0) row = min(row, ROWMAX);
                bb[j] = *(const short8*)&sIn[row * STRIDE + cc * 32 + lk];
            }
#pragma unroll
            for (int j = 0; j < NJ; ++j)
#pragma unroll
                for (int i = 0; i < MF; ++i)
                    acc[i][j] = __builtin_amdgcn_mfma_f32_16x16x32_bf16(a[i], bb[j], acc[i][j], 0, 0, 0);
        }
    }
}

// 1x1 GEMM over the 16 head slots; wave owns 2 m-frags (mf0h, mf0h+1).
__device__ __forceinline__ void gemm_head(const unsigned short* __restrict__ Af,
                                          const unsigned short* __restrict__ s_in,
                                          int mf0h, int lane, f32x4 (&acc)[2])
{
    const int lc = lane & 15;
    const int lk = (lane >> 4) * 8;
    acc[0] = (f32x4){0.f, 0.f, 0.f, 0.f};
    acc[1] = (f32x4){0.f, 0.f, 0.f, 0.f};
#pragma unroll
    for (int cc = 0; cc < 4; ++cc) {
        short8 a[2];
#pragma unroll
        for (int i = 0; i < 2; ++i)
            a[i] = *(const short8*)&Af[(((size_t)cc * 8 + mf0h + i) * 64 + lane) * 8];
        short8 bb = *(const short8*)&s_in[lc * 136 + cc * 32 + lk];
#pragma unroll
        for (int i = 0; i < 2; ++i)
            acc[i] = __builtin_amdgcn_mfma_f32_16x16x32_bf16(a[i], bb, acc[i], 0, 0, 0);
    }
}

// ---------------------------------------------------------------------------
// Megakernel: block = (u 0..63, b 0..31), 256 threads = 4 waves.
// Chunk = 4 final positions. LDS ~20.1 KB -> 8 blocks/CU (grid = exactly 8/CU).
// All phases: each wave owns m-frags {2wid, 2wid+1} (A read exactly once).
// ---------------------------------------------------------------------------
__global__ __launch_bounds__(256)
void mega_kernel(const float* __restrict__ x,
                 const unsigned short* __restrict__ A1, const float* __restrict__ b1,
                 const unsigned short* __restrict__ A2, const float* __restrict__ b2,
                 const unsigned short* __restrict__ A3, const float* __restrict__ b3,
                 const unsigned short* __restrict__ AW1, const float* __restrict__ bo1,
                 const unsigned short* __restrict__ AW2, const float* __restrict__ bo2,
                 const unsigned short* __restrict__ AP,  const float* __restrict__ pn,
                 unsigned* __restrict__ pm_bits)
{
    __shared__ __align__(16) unsigned short s_x[60 * 104];   // x rows [32u-14, 32u+46)
    __shared__ __align__(16) unsigned short s_h1[28 * 136];  // h1 rows [16u-6, 16u+22)
    unsigned short* s_h2 = s_x;           // 12*136 = 1632 shorts (x dead after conv1)
    unsigned short* s_f  = s_x + 1632;    // 16*136 = 2176 shorts (rows 4..15 zero pad)
    float* s_part = (float*)(s_x + 3840); // 64 floats (head phase only)
    float* s_fn   = (float*)(s_x + 3968); // 16 floats

    const int tid  = threadIdx.x;
    const int u    = blockIdx.x;    // 0..63
    const int b    = blockIdx.y;    // 0..31
    const int lane = tid & 63;
    const int wid  = tid >> 6;      // 0..3
    const int mf0  = wid * 2;       // every phase: wave owns m-frags {2wid, 2wid+1}
    const int lc   = lane & 15;
    const int lq   = (lane >> 4) * 4;

    // ---- stage x: rows l in [32u-14, 32u+46), f32 -> bf16, pad 76 -> 96 ch ----
    const int xbase = 32 * u - 14;
    for (int idx = tid; idx < 60 * 24; idx += 256) {
        int pos = idx / 24, c0 = (idx % 24) * 4;
        int l = xbase + pos;
        unsigned short v[4] = {0, 0, 0, 0};
        if (c0 < 76 && l >= 0 && l < 2048) {
            float4 xv = *(const float4*)&x[((size_t)b * 2048 + l) * 76 + c0];
            v[0] = f2bf(xv.x); v[1] = f2bf(xv.y); v[2] = f2bf(xv.z); v[3] = f2bf(xv.w);
        }
        *(uint2*)&s_x[pos * 104 + c0] = *(uint2*)v;
    }
    __syncthreads();

    // ============ conv1: c1 rows [32u-12, 32u+52) computed (keep <32u+44) =====
    {
        f32x4 acc[2][4];
        conv_k<2, 4, 3, 104, 59>(A1, s_x, 0, mf0, lane, acc);  // clamp x row 59

        // bias+relu+pool2 -> s_h1 local rr (global jg = 16u-6+rr), keep rr<28
#pragma unroll
        for (int i = 0; i < 2; ++i) {
            const int ch0 = (mf0 + i) * 16 + lq;
            const f32x4 bv = *(const f32x4*)&b1[ch0];
#pragma unroll
            for (int j = 0; j < 4; ++j) {
                const int nl = j * 16 + lc;
                unsigned short pk[4];
#pragma unroll
                for (int r = 0; r < 4; ++r) {
                    float v = fmaxf(acc[i][j][r] + bv[r], 0.f);
                    float o = __shfl_xor(v, 1);
                    pk[r] = f2bf(fmaxf(v, o));
                }
                if ((lc & 1) == 0) {
                    int rr = nl >> 1;
                    int jg = 16 * u - 6 + rr;
                    if (rr < 28) {
                        uint2 val = (jg >= 0 && jg < 1024) ? *(uint2*)pk : make_uint2(0u, 0u);
                        *(uint2*)&s_h1[rr * 136 + ch0] = val;
                    }
                }
            }
        }
    }
    __syncthreads();   // h1 complete; s_x dead -> s_h2/s_f reusable

    // ============ conv2: c2 rows [16u-4, 16u+28), 4 waves x 2 frags x NJ=2 ====
    {
        // zero s_f pad rows 4..15 (head GEMMs read 16 slots; only 4 are real)
        if (tid < 204) ((uint4*)(s_f + 4 * 136))[tid] = make_uint4(0u, 0u, 0u, 0u);

        f32x4 acc[2][2];
        conv_k<2, 2, 4, 136, 27>(A2, s_h1, 0, mf0, lane, acc);  // clamp h1 row 27

#pragma unroll
        for (int i = 0; i < 2; ++i) {
            const int ch0 = (mf0 + i) * 16 + lq;
            const f32x4 bv = *(const f32x4*)&b2[ch0];
#pragma unroll
            for (int j = 0; j < 2; ++j) {
                const int nl = j * 16 + lc;
                unsigned short pk[4];
#pragma unroll
                for (int r = 0; r < 4; ++r) {
                    float v = fmaxf(acc[i][j][r] + bv[r], 0.f);
                    float o = __shfl_xor(v, 1);
                    pk[r] = f2bf(fmaxf(v, o));
                }
                if ((lc & 1) == 0) {
                    int rr = nl >> 1;             // h2 local, global jg = 8u-2+rr
                    int jg = 8 * u - 2 + rr;
                    if (rr < 12) {
                        uint2 val = (jg >= 0 && jg < 512) ? *(uint2*)pk : make_uint2(0u, 0u);
                        *(uint2*)&s_h2[rr * 136 + ch0] = val;
                    }
                }
            }
        }
    }
    __syncthreads();   // h2 complete

    // ============ conv3: c3 rows [8u, 8u+8), 4 waves x 2 frags x NJ=1 =========
    {
        f32x4 acc[2][1];
        conv_k<2, 1, 4, 136, 11>(A3, s_h2, 0, mf0, lane, acc);  // clamp h2 row 11

#pragma unroll
        for (int i = 0; i < 2; ++i) {
            const int ch0 = (mf0 + i) * 16 + lq;
            const f32x4 bv = *(const f32x4*)&b3[ch0];
            unsigned short pk[4];
#pragma unroll
            for (int r = 0; r < 4; ++r) {
                float v = fmaxf(acc[i][0][r] + bv[r], 0.f);
                float o = __shfl_xor(v, 1);
                pk[r] = f2bf(fmaxf(v, o));
            }
            if ((lc & 1) == 0 && lc < 8)          // only c3 rows 0..7 are real
                *(uint2*)&s_f[(lc >> 1) * 136 + ch0] = *(uint2*)pk;
        }
    }
    __syncthreads();   // f complete (4 positions x 128 ch; rows 4..15 zero)

    // ============ head: wave owns m-frags {2wid, 2wid+1} (r7 structure) =======
    f32x4 hacc[2];

    gemm_head(AW1, s_f, mf0, lane, hacc);     // t1 = relu(Wo1 f + bo1)
    __syncthreads();
#pragma unroll
    for (int i = 0; i < 2; ++i) {
        const int ch0 = (mf0 + i) * 16 + lq;
        const f32x4 bv = *(const f32x4*)&bo1[ch0];
        unsigned short pk[4];
#pragma unroll
        for (int r = 0; r < 4; ++r)
            pk[r] = f2bf(fmaxf(hacc[i][r] + bv[r], 0.f));
        *(uint2*)&s_f[lc * 136 + ch0] = *(uint2*)pk;
    }
    __syncthreads();

    gemm_head(AW2, s_f, mf0, lane, hacc);     // t2 = relu(Wo2 t1 + bo2)
    __syncthreads();
#pragma unroll
    for (int i = 0; i < 2; ++i) {
        const int ch0 = (mf0 + i) * 16 + lq;
        const f32x4 bv = *(const f32x4*)&bo2[ch0];
        unsigned short pk[4];
#pragma unroll
        for (int r = 0; r < 4; ++r)
            pk[r] = f2bf(fmaxf(hacc[i][r] + bv[r], 0.f));
        *(uint2*)&s_f[lc * 136 + ch0] = *(uint2*)pk;
    }
    __syncthreads();

    // fn[n] = ||t2[n]||^2 (n in [0,16); only n<4 are real positions)
    if (tid < 64) {
        int n = tid >> 2, part = tid & 3;
        float s = 0.f;
        for (int c = part * 32; c < part * 32 + 32; ++c) {
            float v = bf2f(s_f[n * 136 + c]);
            s = fmaf(v, v, s);
        }
        s_part[part * 16 + n] = s;
    }
    __syncthreads();
    if (tid < 16)
        s_fn[tid] = s_part[tid] + s_part[16 + tid] + s_part[32 + tid] + s_part[48 + tid];
    __syncthreads();

    gemm_head(AP, s_f, mf0, lane, hacc);      // dot = P t2

    // distances; min over the 4 REAL positions only (lanes lc 0..3 per group)
#pragma unroll
    for (int i = 0; i < 2; ++i) {
        const f32x4 pnv = *(const f32x4*)&pn[(mf0 + i) * 16 + lq];
#pragma unroll
        for (int r = 0; r < 4; ++r) {
            const int p = (mf0 + i) * 16 + lq + r;
            float d2 = s_fn[lc] + pnv[r] - 2.f * hacc[i][r];
            float m = sqrtf(fmaxf(d2, 1e-12f));
#pragma unroll
            for (int s = 1; s < 4; s <<= 1)
                m = fminf(m, __shfl_xor(m, s));
            if (lc == 0)
                atomicMin(&pm_bits[(size_t)b * 128 + p], __float_as_uint(m));
        }
    }
}

// ---------------------------------------------------------------------------
__global__ __launch_bounds__(128)
void finalize_kernel(const float* __restrict__ pm,       // (32,128) global min
                     const int* __restrict__ classes,
                     float* __restrict__ out)            // [64 sigmoid][4096 min_dis]
{
    __shared__ float r0[128], r1[128];
    const int b = blockIdx.x, p = threadIdx.x;
    float m = pm[(size_t)b * 128 + p];
    out[64 + b * 128 + p] = m;

    float sim = logf((m + 1.0f) / (m + 1e-4f));
    int cls = classes[p];
    r0[p] = (cls == 0) ? sim : -0.5f * sim;
    r1[p] = (cls == 1) ? sim : -0.5f * sim;
    __syncthreads();
    for (int s = 64; s > 0; s >>= 1) {
        if (p < s) { r0[p] += r0[p + s]; r1[p] += r1[p + s]; }
        __syncthreads();
    }
    if (p == 0) {
        out[b * 2 + 0] = 1.f / (1.f + expf(-r0[0]));
        out[b * 2 + 1] = 1.f / (1.f + expf(-r1[0]));
    }
}

// ---------------------------------------------------------------------------
extern "C" void kernel_launch(void* const* d_in, const int* in_sizes, int n_in,
                              void* d_out, int out_size, void* d_ws, size_t ws_size,
                              hipStream_t stream)
{
    (void)in_sizes; (void)n_in; (void)out_size; (void)ws_size;
    const float* x    = (const float*)d_in[0];
    const float* W1   = (const float*)d_in[1];
    const float* b1   = (const float*)d_in[2];
    const float* W2   = (const float*)d_in[3];
    const float* b2   = (const float*)d_in[4];
    const float* W3   = (const float*)d_in[5];
    const float* b3   = (const float*)d_in[6];
    const float* Wo1  = (const float*)d_in[7];
    const float* bo1  = (const float*)d_in[8];
    const float* Wo2  = (const float*)d_in[9];
    const float* bo2  = (const float*)d_in[10];
    const float* prot = (const float*)d_in[11];
    const int*   cls  = (const int*)d_in[12];
    float* out = (float*)d_out;

    // ws: A-fragments + pn + pm only (565760 B, identical layout to r5/r7)
    char* ws = (char*)d_ws;
    unsigned short* A1  = (unsigned short*)(ws);
    unsigned short* A2  = (unsigned short*)(ws + 122880);
    unsigned short* A3  = (unsigned short*)(ws + 286720);
    unsigned short* AW1 = (unsigned short*)(ws + 450560);
    unsigned short* AW2 = (unsigned short*)(ws + 483328);
    unsigned short* AP  = (unsigned short*)(ws + 516096);
    float*          pn  = (float*)(ws + 548864);
    unsigned*       pm  = (unsigned*)(ws + 549376);

    prep_weights_kernel<<<dim3(40, 8), 256, 0, stream>>>(W1, W2, W3, Wo1, Wo2, prot,
                                                         A1, A2, A3, AW1, AW2, AP, pn, pm);
    mega_kernel<<<dim3(64, 32), 256, 0, stream>>>(x, A1, b1, A2, b2, A3, b3,
                                                  AW1, bo1, AW2, bo2, AP, pn, pm);
    finalize_kernel<<<32, 128, 0, stream>>>((const float*)pm, cls, out);
}

// Round 10
// 129.786 us; speedup vs baseline: 1.1998x; 1.1998x over previous
//
#include <hip/hip_runtime.h>
#include <cmath>

// ProtICU on MI355X — round 15: r11 base + fence-free merged finalize (one change).
// r14 post-mortem: bundled chunk-4 with r10's known-poison s_cb eviction -> 78us,
// discarded. Attribution matrix: r11 (mega 43.6us) is the plateau of this
// decomposition; r9 = r11 + {2-barrier head, merged finalize WITH __threadfence}
// cost +28us — mechanism: threadfence's L2 writeback x 1024 blocks evicts the
// L2-resident A-fragments all blocks stream. This round merges finalize into
// mega WITHOUT any fence:
//   ordering = per-block atomicMins drained by the s_waitcnt vmcnt(0) the
//   compiler emits before __syncthreads; completion published via device-scope
//   atomicAdd(cnt[b]); 32nd block reads pm_bits via atomicOr(p,0) (device-
//   coherent with the atomicMins). No L2 writeback anywhere.
// Host-gated on ws_size >= 565888 (cnt[] space); else proven 3-kernel fallback.
// Everything else byte-identical to r11 (harness 126.9, mega 43.6, absmax 0.03125).

typedef __attribute__((ext_vector_type(8))) short short8;
typedef __attribute__((ext_vector_type(4))) float f32x4;

__device__ __forceinline__ unsigned short f2bf(float v) {
    union { float f; unsigned u; } x; x.f = v;
    unsigned r = x.u + 0x7fffu + ((x.u >> 16) & 1u);   // RNE
    return (unsigned short)(r >> 16);
}
__device__ __forceinline__ float bf2f(unsigned short b) {
    union { unsigned u; float f; } x; x.u = ((unsigned)b) << 16;
    return x.f;
}

// ---------------------------------------------------------------------------
// Weight packing into MFMA A-fragment order (16x16x32):
// lane holds A[m = mf*16 + (lane&15)][k = cc*32 + (lane>>4)*8 + j]
// conv: dst[((cc*5+kk)*8+mf)*64+lane][8] = W[m][c][kk]   (c >= C -> 0)
// mat : dst[((cc)*8+mf)*64+lane][8] = M[m][c]
// ---------------------------------------------------------------------------
__device__ void pack_conv_w(int t, int total, const float* __restrict__ W, int C,
                            unsigned short* __restrict__ dst)
{
    if (t >= total) return;
    int lane = t & 63, rest = t >> 6;
    int mf = rest & 7; rest >>= 3;
    int kk = rest % 5, cc = rest / 5;
    int m = mf * 16 + (lane & 15);
    int cb = cc * 32 + (lane >> 4) * 8;
    unsigned short v[8];
#pragma unroll
    for (int j = 0; j < 8; ++j) {
        int c = cb + j;
        v[j] = (c < C) ? f2bf(W[((size_t)m * C + c) * 5 + kk]) : (unsigned short)0;
    }
    *(uint4*)&dst[(size_t)t * 8] = *(uint4*)v;
}

__device__ void pack_mat(int t, const float* __restrict__ M, unsigned short* __restrict__ dst)
{
    if (t >= 2048) return;
    int lane = t & 63, mf = (t >> 6) & 7, cc = t >> 9;
    int m = mf * 16 + (lane & 15);
    int c0 = cc * 32 + (lane >> 4) * 8;
    unsigned short v[8];
#pragma unroll
    for (int j = 0; j < 8; ++j) v[j] = f2bf(M[(size_t)m * 128 + c0 + j]);
    *(uint4*)&dst[(size_t)t * 8] = *(uint4*)v;
}

__global__ __launch_bounds__(256)
void prep_weights_kernel(const float* __restrict__ W1, const float* __restrict__ W2,
                         const float* __restrict__ W3, const float* __restrict__ Wo1,
                         const float* __restrict__ Wo2, const float* __restrict__ protos,
                         unsigned short* A1, unsigned short* A2, unsigned short* A3,
                         unsigned short* AW1, unsigned short* AW2, unsigned short* AP,
                         float* pn, unsigned* pm_bits, unsigned* cnt)
{
    int t = blockIdx.x * 256 + threadIdx.x;
    switch (blockIdx.y) {
    case 0: pack_conv_w(t, 7680,  W1, 76,  A1); break;
    case 1: pack_conv_w(t, 10240, W2, 128, A2); break;
    case 2: pack_conv_w(t, 10240, W3, 128, A3); break;
    case 3: pack_mat(t, Wo1, AW1); break;
    case 4: pack_mat(t, Wo2, AW2); break;
    case 5: pack_mat(t, protos, AP); break;
    case 6:
        if (t < 128) {
            float s = 0.f;
            for (int d = 0; d < 128; ++d) {
                float v = bf2f(f2bf(protos[(size_t)t * 128 + d]));
                s = fmaf(v, v, s);
            }
            pn[t] = s;
        }
        break;
    case 7:
        if (t < 4096)             pm_bits[t] = 0x7F800000u;  // +inf for atomicMin
        else if (cnt && t < 4128) cnt[t - 4096] = 0u;        // per-batch counters
        break;
    }
}

// ---------------------------------------------------------------------------
// Conv K-loop (r7 form): wave computes MF m-frags (mf0..mf0+MF-1) x NJ*16 rows
// at nbase. B row (local) = nbase + j*16 + lc + kk, clamped to ROWMAX if >=0.
// ---------------------------------------------------------------------------
template <int MF, int NJ, int NCC, int STRIDE, int ROWMAX>
__device__ __forceinline__ void conv_k(const unsigned short* __restrict__ Af,
                                       const unsigned short* __restrict__ sIn,
                                       int nbase, int mf0, int lane,
                                       f32x4 (&acc)[MF][NJ])
{
    const int lc = lane & 15;
    const int lk = (lane >> 4) * 8;
#pragma unroll
    for (int i = 0; i < MF; ++i)
#pragma unroll
        for (int j = 0; j < NJ; ++j) acc[i][j] = (f32x4){0.f, 0.f, 0.f, 0.f};

    for (int cc = 0; cc < NCC; ++cc) {
#pragma unroll
        for (int kk = 0; kk < 5; ++kk) {
            const int step = cc * 5 + kk;
            short8 a[MF];
#pragma unroll
            for (int i = 0; i < MF; ++i)
                a[i] = *(const short8*)&Af[(((size_t)step * 8 + mf0 + i) * 64 + lane) * 8];
            short8 bb[NJ];
#pragma unroll
            for (int j = 0; j < NJ; ++j) {
                int row = nbase + j * 16 + lc + kk;
                if (ROWMAX >= 0) row = min(row, ROWMAX);
                bb[j] = *(const short8*)&sIn[row * STRIDE + cc * 32 + lk];
            }
#pragma unroll
            for (int j = 0; j < NJ; ++j)
#pragma unroll
                for (int i = 0; i < MF; ++i)
                    acc[i][j] = __builtin_amdgcn_mfma_f32_16x16x32_bf16(a[i], bb[j], acc[i][j], 0, 0, 0);
        }
    }
}

// 1x1 GEMM over the 16 head slots; wave owns 2 m-frags (mf0h, mf0h+1).
__device__ __forceinline__ void gemm_head(const unsigned short* __restrict__ Af,
                                          const unsigned short* __restrict__ s_in,
                                          int mf0h, int lane, f32x4 (&acc)[2])
{
    const int lc = lane & 15;
    const int lk = (lane >> 4) * 8;
    acc[0] = (f32x4){0.f, 0.f, 0.f, 0.f};
    acc[1] = (f32x4){0.f, 0.f, 0.f, 0.f};
#pragma unroll
    for (int cc = 0; cc < 4; ++cc) {
        short8 a[2];
#pragma unroll
        for (int i = 0; i < 2; ++i)
            a[i] = *(const short8*)&Af[(((size_t)cc * 8 + mf0h + i) * 64 + lane) * 8];
        short8 bb = *(const short8*)&s_in[lc * 136 + cc * 32 + lk];
#pragma unroll
        for (int i = 0; i < 2; ++i)
            acc[i] = __builtin_amdgcn_mfma_f32_16x16x32_bf16(a[i], bb, acc[i], 0, 0, 0);
    }
}

// ---------------------------------------------------------------------------
// Megakernel: block = (u 0..31, b 0..31), 256 threads = 4 waves.
// All phases: each wave owns m-frags {2wid, 2wid+1} (A read exactly once).
// ---------------------------------------------------------------------------
__global__ __launch_bounds__(256, 4)
void mega_kernel(const float* __restrict__ x,
                 const unsigned short* __restrict__ A1, const float* __restrict__ b1,
                 const unsigned short* __restrict__ A2, const float* __restrict__ b2,
                 const unsigned short* __restrict__ A3, const float* __restrict__ b3,
                 const unsigned short* __restrict__ AW1, const float* __restrict__ bo1,
                 const unsigned short* __restrict__ AW2, const float* __restrict__ bo2,
                 const unsigned short* __restrict__ AP,  const float* __restrict__ pn,
                 unsigned* __restrict__ pm_bits, unsigned* __restrict__ cnt,
                 const int* __restrict__ classes, float* __restrict__ out)
{
    __shared__ __align__(16) unsigned short s_x[100 * 104];  // x rows [64u-14, 64u+86)
    __shared__ __align__(16) unsigned short s_h1[44 * 136];  // h1 rows [32u-6, 32u+38)
    __shared__ float s_cb[768];      // b1|b2|b3|bo1|bo2|pn
    __shared__ float s_part[64];
    __shared__ float s_fn[16];
    __shared__ unsigned s_last;
    unsigned short* s_h2 = s_x;           // 20*136 = 2720 shorts (x dead after conv1)
    unsigned short* s_f  = s_x + 2720;    // 16*136 = 2176 shorts (rows 8..15 zero pad)

    const int tid  = threadIdx.x;
    const int u    = blockIdx.x;    // 0..31
    const int b    = blockIdx.y;    // 0..31
    const int lane = tid & 63;
    const int wid  = tid >> 6;      // 0..3
    const int mf0  = wid * 2;       // every phase: wave owns m-frags {2wid, 2wid+1}
    const int lc   = lane & 15;
    const int lq   = (lane >> 4) * 4;

    // ---- stage biases + pn ----
    for (int i = tid; i < 768; i += 256) {
        const float* src = (i < 128) ? b1 : (i < 256) ? b2 : (i < 384) ? b3
                         : (i < 512) ? bo1 : (i < 640) ? bo2 : pn;
        s_cb[i] = src[i & 127];
    }

    // ---- stage x: rows l in [64u-14, 64u+86), f32 -> bf16, pad 76 -> 96 ch ----
    const int xbase = 64 * u - 14;
    for (int idx = tid; idx < 100 * 24; idx += 256) {
        int pos = idx / 24, c0 = (idx % 24) * 4;
        int l = xbase + pos;
        unsigned short v[4] = {0, 0, 0, 0};
        if (c0 < 76 && l >= 0 && l < 2048) {
            float4 xv = *(const float4*)&x[((size_t)b * 2048 + l) * 76 + c0];
            v[0] = f2bf(xv.x); v[1] = f2bf(xv.y); v[2] = f2bf(xv.z); v[3] = f2bf(xv.w);
        }
        *(uint2*)&s_x[pos * 104 + c0] = *(uint2*)v;
    }
    __syncthreads();

    // ============ conv1: c1 rows [64u-12, 64u+84), 4 waves x 2 frags x NJ=6 ===
    {
        f32x4 acc[2][6];
        conv_k<2, 6, 3, 104, -1>(A1, s_x, 0, mf0, lane, acc);

        // bias+relu+pool2 -> s_h1 local rr (global jg = 32u-6+rr), keep rr<44
#pragma unroll
        for (int i = 0; i < 2; ++i) {
            const int ch0 = (mf0 + i) * 16 + lq;
#pragma unroll
            for (int j = 0; j < 6; ++j) {
                const int nl = j * 16 + lc;
                unsigned short pk[4];
#pragma unroll
                for (int r = 0; r < 4; ++r) {
                    float v = fmaxf(acc[i][j][r] + s_cb[ch0 + r], 0.f);
                    float o = __shfl_xor(v, 1);
                    pk[r] = f2bf(fmaxf(v, o));
                }
                if ((lc & 1) == 0) {
                    int rr = nl >> 1;
                    int jg = 32 * u - 6 + rr;
                    if (rr < 44) {
                        uint2 val = (jg >= 0 && jg < 1024) ? *(uint2*)pk : make_uint2(0u, 0u);
                        *(uint2*)&s_h1[rr * 136 + ch0] = val;
                    }
                }
            }
        }
    }
    __syncthreads();   // h1 complete; s_x dead -> s_h2/s_f reusable

    // ============ conv2: c2 rows [32u-4, 32u+44), all 4 waves, 2 frags each ===
    {
        // zero s_f pad rows 8..15 (head GEMMs read 16 slots; only 8 are real)
        if (tid < 136) ((uint4*)(s_f + 8 * 136))[tid] = make_uint4(0u, 0u, 0u, 0u);

        f32x4 acc[2][3];
        conv_k<2, 3, 4, 136, 43>(A2, s_h1, 0, mf0, lane, acc);

#pragma unroll
        for (int i = 0; i < 2; ++i) {
            const int ch0 = (mf0 + i) * 16 + lq;
#pragma unroll
            for (int j = 0; j < 3; ++j) {
                const int nl = j * 16 + lc;
                unsigned short pk[4];
#pragma unroll
                for (int r = 0; r < 4; ++r) {
                    float v = fmaxf(acc[i][j][r] + s_cb[128 + ch0 + r], 0.f);
                    float o = __shfl_xor(v, 1);
                    pk[r] = f2bf(fmaxf(v, o));
                }
                if ((lc & 1) == 0) {
                    int rr = nl >> 1;             // h2 local, global jg = 16u-2+rr
                    int jg = 16 * u - 2 + rr;
                    if (rr < 20) {
                        uint2 val = (jg >= 0 && jg < 512) ? *(uint2*)pk : make_uint2(0u, 0u);
                        *(uint2*)&s_h2[rr * 136 + ch0] = val;
                    }
                }
            }
        }
    }
    __syncthreads();   // h2 complete

    // ============ conv3: c3 rows [16u, 16u+16), all 4 waves, 2 frags each =====
    {
        f32x4 acc[2][1];
        conv_k<2, 1, 4, 136, -1>(A3, s_h2, 0, mf0, lane, acc);

#pragma unroll
        for (int i = 0; i < 2; ++i) {
            const int ch0 = (mf0 + i) * 16 + lq;
            unsigned short pk[4];
#pragma unroll
            for (int r = 0; r < 4; ++r) {
                float v = fmaxf(acc[i][0][r] + s_cb[256 + ch0 + r], 0.f);
                float o = __shfl_xor(v, 1);
                pk[r] = f2bf(fmaxf(v, o));
            }
            if ((lc & 1) == 0)
                *(uint2*)&s_f[(lc >> 1) * 136 + ch0] = *(uint2*)pk;
        }
    }
    __syncthreads();   // f complete (8 positions x 128 ch; rows 8..15 zero)

    // ============ head: wave owns m-frags {2wid, 2wid+1} (r7 structure) =======
    f32x4 hacc[2];

    gemm_head(AW1, s_f, mf0, lane, hacc);     // t1 = relu(Wo1 f + bo1)
    __syncthreads();
#pragma unroll
    for (int i = 0; i < 2; ++i) {
        const int ch0 = (mf0 + i) * 16 + lq;
        unsigned short pk[4];
#pragma unroll
        for (int r = 0; r < 4; ++r)
            pk[r] = f2bf(fmaxf(hacc[i][r] + s_cb[384 + ch0 + r], 0.f));
        *(uint2*)&s_f[lc * 136 + ch0] = *(uint2*)pk;
    }
    __syncthreads();

    gemm_head(AW2, s_f, mf0, lane, hacc);     // t2 = relu(Wo2 t1 + bo2)
    __syncthreads();
#pragma unroll
    for (int i = 0; i < 2; ++i) {
        const int ch0 = (mf0 + i) * 16 + lq;
        unsigned short pk[4];
#pragma unroll
        for (int r = 0; r < 4; ++r)
            pk[r] = f2bf(fmaxf(hacc[i][r] + s_cb[512 + ch0 + r], 0.f));
        *(uint2*)&s_f[lc * 136 + ch0] = *(uint2*)pk;
    }
    __syncthreads();

    // fn[n] = ||t2[n]||^2 (n in [0,16); only n<8 are real positions)
    if (tid < 64) {
        int n = tid >> 2, part = tid & 3;
        float s = 0.f;
        for (int c = part * 32; c < part * 32 + 32; ++c) {
            float v = bf2f(s_f[n * 136 + c]);
            s = fmaf(v, v, s);
        }
        s_part[part * 16 + n] = s;
    }
    __syncthreads();
    if (tid < 16)
        s_fn[tid] = s_part[tid] + s_part[16 + tid] + s_part[32 + tid] + s_part[48 + tid];
    __syncthreads();

    gemm_head(AP, s_f, mf0, lane, hacc);      // dot = P t2

    // distances; min over the 8 REAL positions only (lanes lc 0..7 per group)
#pragma unroll
    for (int i = 0; i < 2; ++i) {
#pragma unroll
        for (int r = 0; r < 4; ++r) {
            const int p = (mf0 + i) * 16 + lq + r;
            float d2 = s_fn[lc] + s_cb[640 + p] - 2.f * hacc[i][r];
            float m = sqrtf(fmaxf(d2, 1e-12f));
#pragma unroll
            for (int s = 1; s < 8; s <<= 1)
                m = fminf(m, __shfl_xor(m, s));
            if (lc == 0)
                atomicMin(&pm_bits[(size_t)b * 128 + p], __float_as_uint(m));
        }
    }

    // ============ merged finalize: NO threadfence (the r9 poison) =============
    // __syncthreads drains vmcnt(0) (compiler-emitted before s_barrier), so all
    // this block's atomicMins have completed at the device coherence point
    // before tid 0 publishes via the device-scope atomicAdd below.
    if (cnt) {
        __syncthreads();
        if (tid == 0) s_last = atomicAdd(&cnt[b], 1u);
        __syncthreads();
        if (s_last == 31u) {
            float* r0 = (float*)s_h1;     // s_h1 dead, reuse as reduction scratch
            float* r1 = r0 + 128;
            if (tid < 128) {
                unsigned mb = atomicOr(&pm_bits[(size_t)b * 128 + tid], 0u);  // coherent read
                float m = __uint_as_float(mb);
                out[64 + b * 128 + tid] = m;
                float sim = logf((m + 1.0f) / (m + 1e-4f));
                int c = classes[tid];
                r0[tid] = (c == 0) ? sim : -0.5f * sim;
                r1[tid] = (c == 1) ? sim : -0.5f * sim;
            }
            __syncthreads();
            for (int s = 64; s > 0; s >>= 1) {
                if (tid < s) { r0[tid] += r0[tid + s]; r1[tid] += r1[tid + s]; }
                __syncthreads();
            }
            if (tid == 0) {
                out[b * 2 + 0] = 1.f / (1.f + expf(-r0[0]));
                out[b * 2 + 1] = 1.f / (1.f + expf(-r1[0]));
            }
        }
    }
}

// ---------------------------------------------------------------------------
__global__ __launch_bounds__(128)
void finalize_kernel(const float* __restrict__ pm,       // (32,128) global min
                     const int* __restrict__ classes,
                     float* __restrict__ out)            // [64 sigmoid][4096 min_dis]
{
    __shared__ float r0[128], r1[128];
    const int b = blockIdx.x, p = threadIdx.x;
    float m = pm[(size_t)b * 128 + p];
    out[64 + b * 128 + p] = m;

    float sim = logf((m + 1.0f) / (m + 1e-4f));
    int cls = classes[p];
    r0[p] = (cls == 0) ? sim : -0.5f * sim;
    r1[p] = (cls == 1) ? sim : -0.5f * sim;
    __syncthreads();
    for (int s = 64; s > 0; s >>= 1) {
        if (p < s) { r0[p] += r0[p + s]; r1[p] += r1[p + s]; }
        __syncthreads();
    }
    if (p == 0) {
        out[b * 2 + 0] = 1.f / (1.f + expf(-r0[0]));
        out[b * 2 + 1] = 1.f / (1.f + expf(-r1[0]));
    }
}

// ---------------------------------------------------------------------------
extern "C" void kernel_launch(void* const* d_in, const int* in_sizes, int n_in,
                              void* d_out, int out_size, void* d_ws, size_t ws_size,
                              hipStream_t stream)
{
    (void)in_sizes; (void)n_in; (void)out_size;
    const float* x    = (const float*)d_in[0];
    const float* W1   = (const float*)d_in[1];
    const float* b1   = (const float*)d_in[2];
    const float* W2   = (const float*)d_in[3];
    const float* b2   = (const float*)d_in[4];
    const float* W3   = (const float*)d_in[5];
    const float* b3   = (const float*)d_in[6];
    const float* Wo1  = (const float*)d_in[7];
    const float* bo1  = (const float*)d_in[8];
    const float* Wo2  = (const float*)d_in[9];
    const float* bo2  = (const float*)d_in[10];
    const float* prot = (const float*)d_in[11];
    const int*   cls  = (const int*)d_in[12];
    float* out = (float*)d_out;

    // ws: A-fragments + pn + pm (565760 B, identical to r11) [+ cnt if room]
    char* ws = (char*)d_ws;
    unsigned short* A1  = (unsigned short*)(ws);
    unsigned short* A2  = (unsigned short*)(ws + 122880);
    unsigned short* A3  = (unsigned short*)(ws + 286720);
    unsigned short* AW1 = (unsigned short*)(ws + 450560);
    unsigned short* AW2 = (unsigned short*)(ws + 483328);
    unsigned short* AP  = (unsigned short*)(ws + 516096);
    float*          pn  = (float*)(ws + 548864);
    unsigned*       pm  = (unsigned*)(ws + 549376);
    const bool merged = (ws_size >= 565760u + 128u);
    unsigned*       cnt = merged ? (unsigned*)(ws + 565760) : nullptr;

    prep_weights_kernel<<<dim3(40, 8), 256, 0, stream>>>(W1, W2, W3, Wo1, Wo2, prot,
                                                         A1, A2, A3, AW1, AW2, AP, pn, pm, cnt);
    mega_kernel<<<dim3(32, 32), 256, 0, stream>>>(x, A1, b1, A2, b2, A3, b3,
                                                  AW1, bo1, AW2, bo2, AP, pn, pm, cnt,
                                                  cls, out);
    if (!merged)
        finalize_kernel<<<32, 128, 0, stream>>>((const float*)pm, cls, out);
}